// Round 3
// baseline (279.134 us; speedup 1.0000x reference)
//
#include <hip/hip_runtime.h>
#include <math.h>

// Problem constants
#define T_DIM 1024
#define N_DIM 8192
#define M_TOT (T_DIM * N_DIM)          // 8,388,608
#define NV2   (N_DIM / 2)              // 4096 float2 per row
#define NV4   (N_DIM / 4)              // 2048 float4 per row (scan view)
#define L_CHUNK 8
#define C_CHUNKS (T_DIM / L_CHUNK)     // 128
#define PC_BLOCKS ((C_CHUNKS * NV2) / 256)   // 2048  (8 blocks/CU -> 8 waves/SIMD)
#define SCAN_BLOCKS ((NV4 * 32) / 256)       // 256

#define kGAMMA 0.99f
#define kGLAM  (0.99f * 0.95f)

// ws layout (~24.2 MB):
//   +1024          pg [2048][3] doubles (48 KB)  -- k_gae block partials
//   +65536         pl [2048][2] doubles (32 KB)  -- k_loss block partials
//   +131072        b16 [T][N] ushort (16 MB)     -- persists through k_loss
//   +131072+16MB   A   [C][N] float (4 MB)       -- chunk-map A, overwritten w/ g_in
//   +131072+20MB   B   [C][N] float (4 MB)

__device__ __forceinline__ unsigned short f2bf(float f) {
    unsigned int u = __float_as_uint(f);
    u += 0x7fffu + ((u >> 16) & 1u);        // round-to-nearest-even
    return (unsigned short)(u >> 16);
}
__device__ __forceinline__ float bf2f(unsigned short h) {
    return __uint_as_float(((unsigned int)h) << 16);
}

// ---------------------------------------------------------------------------
// K1: fused prep+chunk, float2 geometry. Thread (c, jj): row-serial
// descending-t loop with vnext carry; emits b_t (bf16, a-bit in LSB, two
// packed per uint) AND the chunk map (A,B). 2048 blocks -> 8 waves/SIMD.
__global__ __launch_bounds__(256, 8) void k_pc(
    const float2* __restrict__ r2,
    const float2* __restrict__ m2,     // (T+1) rows
    const float2* __restrict__ bm2,    // (T+1) rows
    const float2* __restrict__ vp2,    // (T+1) rows
    const float2* __restrict__ lv2,    // (N,)
    unsigned int* __restrict__ b16,    // [T][N/2] two bf16 per uint
    float2* __restrict__ A_out,
    float2* __restrict__ B_out)
{
    const int g  = blockIdx.x * 256 + threadIdx.x;   // 0 .. C*NV2-1
    const int jj = g & (NV2 - 1);
    const int c  = g >> 12;
    const int t0 = c * L_CHUNK;

    float2 vnext = (c == C_CHUNKS - 1) ? lv2[jj] : vp2[(t0 + L_CHUNK) * NV2 + jj];
    float2 Aa = make_float2(1.f, 1.f);
    float2 Bb = make_float2(0.f, 0.f);

    #pragma unroll
    for (int i = L_CHUNK - 1; i >= 0; --i) {
        const int idx = (t0 + i) * NV2 + jj;
        const float2 r  = r2[idx];
        const float2 v  = vp2[idx];
        const float2 m  = m2[idx + NV2];             // row t+1
        const float2 bb = bm2[idx + NV2];            // row t+1

        unsigned int hx, hy;
        {
            const float b = (fmaf(kGAMMA * m.x, vnext.x, r.x) - v.x) * bb.x;
            const float a = kGLAM * m.x * bb.x;
            Aa.x = a * Aa.x; Bb.x = fmaf(a, Bb.x, b);
            hx = (unsigned int)((f2bf(b) & 0xFFFEu) | ((m.x * bb.x > 0.5f) ? 1u : 0u));
        }
        {
            const float b = (fmaf(kGAMMA * m.y, vnext.y, r.y) - v.y) * bb.y;
            const float a = kGLAM * m.y * bb.y;
            Aa.y = a * Aa.y; Bb.y = fmaf(a, Bb.y, b);
            hy = (unsigned int)((f2bf(b) & 0xFFFEu) | ((m.y * bb.y > 0.5f) ? 1u : 0u));
        }
        b16[idx] = hx | (hy << 16);
        vnext = v;
    }
    A_out[c * NV2 + jj] = Aa;
    B_out[c * NV2 + jj] = Bb;
}

// ---------------------------------------------------------------------------
// K2: parallel suffix scan of the 128 affine chunk maps (float4 view of A/B).
// Thread (jj, k): slice k = chunks 4k..4k+3 of vec4-env jj; 32-lane shuffle
// groups share one jj. g_in overwrites Ag (one thread owns each slot).
__global__ __launch_bounds__(256, 8) void k_scan(
    float4* __restrict__ Ag,           // in: A, out: g_in
    const float4* __restrict__ Bg)
{
    const int u  = blockIdx.x * 256 + threadIdx.x;   // 0 .. NV4*32-1
    const int jj = u >> 5;
    const int k  = u & 31;

    float4 As[4], Bs[4];
    #pragma unroll
    for (int i = 0; i < 4; ++i) {
        As[i] = Ag[(4 * k + i) * NV4 + jj];
        Bs[i] = Bg[(4 * k + i) * NV4 + jj];
    }
    // slice map M_k = f_{4k} o ... o f_{4k+3} (highest chunk applied first)
    float4 Pa = As[3], Pb = Bs[3];
    #pragma unroll
    for (int i = 2; i >= 0; --i) {
        Pb.x = fmaf(As[i].x, Pb.x, Bs[i].x); Pa.x = As[i].x * Pa.x;
        Pb.y = fmaf(As[i].y, Pb.y, Bs[i].y); Pa.y = As[i].y * Pa.y;
        Pb.z = fmaf(As[i].z, Pb.z, Bs[i].z); Pa.z = As[i].z * Pa.z;
        Pb.w = fmaf(As[i].w, Pb.w, Bs[i].w); Pa.w = As[i].w * Pa.w;
    }
    // inclusive suffix scan across 32 slices: P_k = M_k o M_{k+1} o ... o M_31
    #pragma unroll
    for (int d = 1; d < 32; d <<= 1) {
        const float nax = __shfl_down(Pa.x, d, 32), nay = __shfl_down(Pa.y, d, 32);
        const float naz = __shfl_down(Pa.z, d, 32), naw = __shfl_down(Pa.w, d, 32);
        const float nbx = __shfl_down(Pb.x, d, 32), nby = __shfl_down(Pb.y, d, 32);
        const float nbz = __shfl_down(Pb.z, d, 32), nbw = __shfl_down(Pb.w, d, 32);
        if (k + d < 32) {               // compose: current o neighbor
            Pb.x = fmaf(Pa.x, nbx, Pb.x); Pa.x *= nax;
            Pb.y = fmaf(Pa.y, nby, Pb.y); Pa.y *= nay;
            Pb.z = fmaf(Pa.z, nbz, Pb.z); Pa.z *= naz;
            Pb.w = fmaf(Pa.w, nbw, Pb.w); Pa.w *= naw;
        }
    }
    // incoming gae for slice k = P_{k+1}(0) = B of lane k+1 (0 for k==31)
    float4 G;
    G.x = __shfl_down(Pb.x, 1, 32);
    G.y = __shfl_down(Pb.y, 1, 32);
    G.z = __shfl_down(Pb.z, 1, 32);
    G.w = __shfl_down(Pb.w, 1, 32);
    if (k == 31) G = make_float4(0.f, 0.f, 0.f, 0.f);
    // back-fill per-chunk incoming gae
    #pragma unroll
    for (int i = 3; i >= 0; --i) {
        Ag[(4 * k + i) * NV4 + jj] = G;
        G.x = fmaf(As[i].x, G.x, Bs[i].x);
        G.y = fmaf(As[i].y, G.y, Bs[i].y);
        G.z = fmaf(As[i].z, G.z, Bs[i].z);
        G.w = fmaf(As[i].w, G.w, Bs[i].w);
    }
}

// ---------------------------------------------------------------------------
// K3: recompute gae from b16 + g_in (row-serial, float2 geometry); fuse value
// loss and sum/sum2 of gae. Block partials -> pg. No gae store.
__device__ __forceinline__ void gae_comp(float& gae, unsigned short h,
                                         float v, float nvv,
                                         float& sg, float& sg2, float& v_s) {
    const float bf = bf2f(h);
    const float a  = (h & 1u) ? kGLAM : 0.0f;
    gae = fmaf(a, gae, bf);
    sg += gae;
    sg2 = fmaf(gae, gae, sg2);
    const float q  = nvv - v;
    const float e1 = q - gae;
    const float e2 = fminf(fmaxf(q, -0.2f), 0.2f) - gae;
    v_s += fmaxf(e1 * e1, e2 * e2);
}

__global__ __launch_bounds__(256, 8) void k_gae(
    const unsigned int* __restrict__ b16,
    const float2* __restrict__ g_in2,
    const float2* __restrict__ vp2,
    const float2* __restrict__ nv2,
    double* __restrict__ pg)           // [PC_BLOCKS][3]
{
    const int g  = blockIdx.x * 256 + threadIdx.x;
    const int jj = g & (NV2 - 1);
    const int c  = g >> 12;
    const int t0 = c * L_CHUNK;

    float2 gae = g_in2[c * NV2 + jj];
    float sg = 0.f, sg2 = 0.f, v_s = 0.f;

    #pragma unroll
    for (int i = L_CHUNK - 1; i >= 0; --i) {
        const int idx = (t0 + i) * NV2 + jj;
        const unsigned int h = b16[idx];
        const float2 v = vp2[idx];
        const float2 q = nv2[idx];
        gae_comp(gae.x, (unsigned short)(h & 0xFFFFu), v.x, q.x, sg, sg2, v_s);
        gae_comp(gae.y, (unsigned short)(h >> 16),     v.y, q.y, sg, sg2, v_s);
    }

    double d0 = (double)sg, d1 = (double)sg2, d2 = (double)v_s;
    #pragma unroll
    for (int off = 32; off > 0; off >>= 1) {
        d0 += __shfl_down(d0, off, 64);
        d1 += __shfl_down(d1, off, 64);
        d2 += __shfl_down(d2, off, 64);
    }
    __shared__ double sh[3][4];
    const int wid = threadIdx.x >> 6, lane = threadIdx.x & 63;
    if (lane == 0) { sh[0][wid] = d0; sh[1][wid] = d1; sh[2][wid] = d2; }
    __syncthreads();
    if (threadIdx.x == 0) {
        double t0s = 0, t1s = 0, t2s = 0;
        #pragma unroll
        for (int w = 0; w < 4; ++w) { t0s += sh[0][w]; t1s += sh[1][w]; t2s += sh[2][w]; }
        pg[blockIdx.x * 3 + 0] = t0s;
        pg[blockIdx.x * 3 + 1] = t1s;
        pg[blockIdx.x * 3 + 2] = t2s;
    }
}

// ---------------------------------------------------------------------------
// K4: action loss + entropy (float2 geometry). Absorbs k_stats: every block
// redundantly reduces the 48 KB pg partials (L2-resident) to mu/invs, then
// recomputes gae in fp32 from b16 + g_in. Partials -> pl.
__global__ __launch_bounds__(256, 8) void k_loss(
    const unsigned int* __restrict__ b16,
    const float2* __restrict__ g_in2,
    const float2* __restrict__ lp2,
    const float2* __restrict__ plp2,
    const float2* __restrict__ ent2,
    const double* __restrict__ pg,
    double* __restrict__ pl)           // [PC_BLOCKS][2]
{
    __shared__ double sh[2][4];
    __shared__ double bc[2];
    const int tid = threadIdx.x;

    // --- redundant stats reduce (mu, invs) ---
    {
        double s0 = 0.0, s1 = 0.0;
        for (int i = tid; i < PC_BLOCKS; i += 256) {
            s0 += pg[i * 3 + 0];
            s1 += pg[i * 3 + 1];
        }
        #pragma unroll
        for (int off = 32; off > 0; off >>= 1) {
            s0 += __shfl_down(s0, off, 64);
            s1 += __shfl_down(s1, off, 64);
        }
        const int wid = tid >> 6, lane = tid & 63;
        if (lane == 0) { sh[0][wid] = s0; sh[1][wid] = s1; }
        __syncthreads();
        if (tid == 0) {
            double sum = 0, sum2 = 0;
            #pragma unroll
            for (int w = 0; w < 4; ++w) { sum += sh[0][w]; sum2 += sh[1][w]; }
            const double M = (double)M_TOT;
            const double mu = sum / M;
            double var = (sum2 - sum * sum / M) / (M - 1.0);
            if (var < 0.0) var = 0.0;
            bc[0] = mu;
            bc[1] = 1.0 / (sqrt(var) + 1e-5);
        }
        __syncthreads();
    }
    const float mu   = (float)bc[0];
    const float invs = (float)bc[1];

    // --- loss over this block's chunk (same geometry as K3) ---
    const int g  = blockIdx.x * 256 + tid;
    const int jj = g & (NV2 - 1);
    const int c  = g >> 12;
    const int t0 = c * L_CHUNK;

    float2 gv = g_in2[c * NV2 + jj];
    float a_s = 0.f, e_s = 0.f;

    #pragma unroll
    for (int i = L_CHUNK - 1; i >= 0; --i) {
        const int idx = (t0 + i) * NV2 + jj;
        const unsigned int h = b16[idx];
        const float2 Lp = lp2[idx];
        const float2 Pp = plp2[idx];
        const float2 E  = ent2[idx];
#define P5C(comp, H) { \
        const unsigned short hh = (unsigned short)(H); \
        const float bf = bf2f(hh); \
        const float a  = (hh & 1u) ? kGLAM : 0.0f; \
        gv.comp = fmaf(a, gv.comp, bf); \
        const float x  = (gv.comp - mu) * invs; \
        const float rr = __expf(Lp.comp - Pp.comp); \
        const float rc = fminf(fmaxf(rr, 0.8f), 1.2f); \
        a_s += fminf(rr * x, rc * x); }
        P5C(x, h & 0xFFFFu) P5C(y, h >> 16)
#undef P5C
        e_s += E.x + E.y;
    }

    double d0 = (double)a_s, d1 = (double)e_s;
    #pragma unroll
    for (int off = 32; off > 0; off >>= 1) {
        d0 += __shfl_down(d0, off, 64);
        d1 += __shfl_down(d1, off, 64);
    }
    const int wid = tid >> 6, lane = tid & 63;
    if (lane == 0) { sh[0][wid] = d0; sh[1][wid] = d1; }
    __syncthreads();
    if (tid == 0) {
        double t0s = 0, t1s = 0;
        #pragma unroll
        for (int w = 0; w < 4; ++w) { t0s += sh[0][w]; t1s += sh[1][w]; }
        pl[blockIdx.x * 2 + 0] = t0s;
        pl[blockIdx.x * 2 + 1] = t1s;
    }
}

// ---------------------------------------------------------------------------
// K5: reduce k_gae vsum partials + k_loss partials -> final scalar.
__global__ __launch_bounds__(256) void k_final(
    const double* __restrict__ pg, const double* __restrict__ pl,
    float* __restrict__ out)
{
    double s0 = 0.0, s1 = 0.0, s2 = 0.0;
    for (int i = threadIdx.x; i < PC_BLOCKS; i += 256) {
        s0 += pl[i * 2 + 0];
        s1 += pl[i * 2 + 1];
        s2 += pg[i * 3 + 2];
    }
    #pragma unroll
    for (int off = 32; off > 0; off >>= 1) {
        s0 += __shfl_down(s0, off, 64);
        s1 += __shfl_down(s1, off, 64);
        s2 += __shfl_down(s2, off, 64);
    }
    __shared__ double sh[3][4];
    const int wid = threadIdx.x >> 6, lane = threadIdx.x & 63;
    if (lane == 0) { sh[0][wid] = s0; sh[1][wid] = s1; sh[2][wid] = s2; }
    __syncthreads();
    if (threadIdx.x == 0) {
        double a_sum = 0, e_sum = 0, vsum = 0;
        #pragma unroll
        for (int w = 0; w < 4; ++w) { a_sum += sh[0][w]; e_sum += sh[1][w]; vsum += sh[2][w]; }
        const double M = (double)M_TOT;
        out[0] = (float)(0.25 * vsum / M - a_sum / M - 0.01 * e_sum / M);
    }
}

// ---------------------------------------------------------------------------
extern "C" void kernel_launch(void* const* d_in, const int* in_sizes, int n_in,
                              void* d_out, int out_size, void* d_ws, size_t ws_size,
                              hipStream_t stream) {
    const float* rewards     = (const float*)d_in[0];   // (T, N)
    const float* masks       = (const float*)d_in[1];   // (T+1, N)
    const float* bad_masks   = (const float*)d_in[2];   // (T+1, N)
    const float* value_preds = (const float*)d_in[3];   // (T+1, N)
    const float* last_value  = (const float*)d_in[4];   // (N,)
    const float* log_prob    = (const float*)d_in[5];   // (T, N)
    const float* prev_lp     = (const float*)d_in[6];   // (T, N)
    const float* new_value   = (const float*)d_in[7];   // (T, N)
    const float* dist_ent    = (const float*)d_in[8];   // (T, N)

    char* ws = (char*)d_ws;
    double* pg = (double*)(ws + 1024);
    double* pl = (double*)(ws + 65536);
    unsigned int* b16 = (unsigned int*)(ws + 131072);
    float* A = (float*)(ws + 131072 + (size_t)M_TOT * 2);
    float* B = (float*)(ws + 131072 + (size_t)M_TOT * 2 + (size_t)C_CHUNKS * N_DIM * 4);

    k_pc<<<PC_BLOCKS, 256, 0, stream>>>((const float2*)rewards,
                                        (const float2*)masks,
                                        (const float2*)bad_masks,
                                        (const float2*)value_preds,
                                        (const float2*)last_value,
                                        b16, (float2*)A, (float2*)B);
    k_scan<<<SCAN_BLOCKS, 256, 0, stream>>>((float4*)A, (const float4*)B);
    k_gae<<<PC_BLOCKS, 256, 0, stream>>>(b16,
                                         (const float2*)A /* g_in */,
                                         (const float2*)value_preds,
                                         (const float2*)new_value, pg);
    k_loss<<<PC_BLOCKS, 256, 0, stream>>>(b16,
                                          (const float2*)A /* g_in */,
                                          (const float2*)log_prob,
                                          (const float2*)prev_lp,
                                          (const float2*)dist_ent, pg, pl);
    k_final<<<1, 256, 0, stream>>>(pg, pl, (float*)d_out);
}

// Round 4
// 273.966 us; speedup vs baseline: 1.0189x; 1.0189x over previous
//
#include <hip/hip_runtime.h>
#include <math.h>

// Problem constants
#define T_DIM 1024
#define N_DIM 8192
#define M_TOT (T_DIM * N_DIM)          // 8,388,608
#define NV4   (N_DIM / 4)              // 2048 float4 per row
#define L_CHUNK 4
#define C_CHUNKS (T_DIM / L_CHUNK)     // 256
#define PC_BLOCKS ((C_CHUNKS * NV4) / 256)   // 2048  (8 blocks/CU target)
#define SCAN_BLOCKS ((NV4 * 32) / 256)       // 256   (32 slices of 8 chunks)

#define kGAMMA 0.99f
#define kGLAM  (0.99f * 0.95f)

// ws layout (~33.7 MB):
//   +1024          pg [2048][3] doubles (48 KB)  -- k_gae block partials
//   +65536         pl [2048][2] doubles (32 KB)  -- k_loss block partials
//   +131072        b16 [T][N] ushort (16 MB)     -- persists through k_loss
//   +131072+16MB   A   [C][N] float (8 MB)       -- chunk-map A, overwritten w/ g_in
//   +131072+24MB   B   [C][N] float (8 MB)

__device__ __forceinline__ unsigned short f2bf(float f) {
    unsigned int u = __float_as_uint(f);
    u += 0x7fffu + ((u >> 16) & 1u);        // round-to-nearest-even
    return (unsigned short)(u >> 16);
}
__device__ __forceinline__ float bf2f(unsigned short h) {
    return __uint_as_float(((unsigned int)h) << 16);
}

// ---------------------------------------------------------------------------
// K1: fused prep+chunk, float4 geometry (proven write-exact), L_CHUNK=4.
// No vnext carry: vp[idx+NV4] is loaded per-iteration (L1-hit on the next
// iteration's v load) so all 4 iterations are fully independent -> deep MLP.
__global__ __launch_bounds__(256, 6) void k_pc(
    const float4* __restrict__ r4,
    const float4* __restrict__ m4,     // (T+1) rows
    const float4* __restrict__ bm4,    // (T+1) rows
    const float4* __restrict__ vp4,    // (T+1) rows
    const float4* __restrict__ lv4,    // (N,)
    ushort4* __restrict__ b16,
    float4* __restrict__ A_out,
    float4* __restrict__ B_out)
{
    const int g  = blockIdx.x * 256 + threadIdx.x;   // 0 .. C*NV4-1
    const int j  = g & (NV4 - 1);
    const int c  = g >> 11;
    const int t0 = c * L_CHUNK;
    const bool last_c = (c == C_CHUNKS - 1);

    float4 Aa = make_float4(1.f, 1.f, 1.f, 1.f);
    float4 Bb = make_float4(0.f, 0.f, 0.f, 0.f);

    #pragma unroll
    for (int i = L_CHUNK - 1; i >= 0; --i) {
        const int idx = (t0 + i) * NV4 + j;
        const float4 r  = r4[idx];
        const float4 v  = vp4[idx];
        const float4 vn = (last_c && i == L_CHUNK - 1) ? lv4[j]
                                                       : vp4[idx + NV4];
        const float4 m  = m4[idx + NV4];             // row t+1
        const float4 bb = bm4[idx + NV4];            // row t+1

        ushort4 o;
        {
            const float b = (fmaf(kGAMMA * m.x, vn.x, r.x) - v.x) * bb.x;
            const float a = kGLAM * m.x * bb.x;
            Aa.x = a * Aa.x; Bb.x = fmaf(a, Bb.x, b);
            o.x = (unsigned short)((f2bf(b) & 0xFFFEu) | ((m.x * bb.x > 0.5f) ? 1u : 0u));
        }
        {
            const float b = (fmaf(kGAMMA * m.y, vn.y, r.y) - v.y) * bb.y;
            const float a = kGLAM * m.y * bb.y;
            Aa.y = a * Aa.y; Bb.y = fmaf(a, Bb.y, b);
            o.y = (unsigned short)((f2bf(b) & 0xFFFEu) | ((m.y * bb.y > 0.5f) ? 1u : 0u));
        }
        {
            const float b = (fmaf(kGAMMA * m.z, vn.z, r.z) - v.z) * bb.z;
            const float a = kGLAM * m.z * bb.z;
            Aa.z = a * Aa.z; Bb.z = fmaf(a, Bb.z, b);
            o.z = (unsigned short)((f2bf(b) & 0xFFFEu) | ((m.z * bb.z > 0.5f) ? 1u : 0u));
        }
        {
            const float b = (fmaf(kGAMMA * m.w, vn.w, r.w) - v.w) * bb.w;
            const float a = kGLAM * m.w * bb.w;
            Aa.w = a * Aa.w; Bb.w = fmaf(a, Bb.w, b);
            o.w = (unsigned short)((f2bf(b) & 0xFFFEu) | ((m.w * bb.w > 0.5f) ? 1u : 0u));
        }
        b16[idx] = o;
    }
    A_out[c * NV4 + j] = Aa;
    B_out[c * NV4 + j] = Bb;
}

// ---------------------------------------------------------------------------
// K2: parallel suffix scan of the 256 affine chunk maps. Thread (jj, k):
// slice k = chunks 8k..8k+7 of vec4-env jj; 32-lane shuffle groups share one
// jj. g_in overwrites Ag (one thread owns each slot). Scan algebra identical
// to the round-3 version that verified bit-exact.
__global__ __launch_bounds__(256, 4) void k_scan(
    float4* __restrict__ Ag,           // in: A, out: g_in
    const float4* __restrict__ Bg)
{
    const int u  = blockIdx.x * 256 + threadIdx.x;   // 0 .. NV4*32-1
    const int jj = u >> 5;
    const int k  = u & 31;

    float4 As[8], Bs[8];
    #pragma unroll
    for (int i = 0; i < 8; ++i) {
        As[i] = Ag[(8 * k + i) * NV4 + jj];
        Bs[i] = Bg[(8 * k + i) * NV4 + jj];
    }
    // slice map M_k = f_{8k} o ... o f_{8k+7} (highest chunk applied first)
    float4 Pa = As[7], Pb = Bs[7];
    #pragma unroll
    for (int i = 6; i >= 0; --i) {
        Pb.x = fmaf(As[i].x, Pb.x, Bs[i].x); Pa.x = As[i].x * Pa.x;
        Pb.y = fmaf(As[i].y, Pb.y, Bs[i].y); Pa.y = As[i].y * Pa.y;
        Pb.z = fmaf(As[i].z, Pb.z, Bs[i].z); Pa.z = As[i].z * Pa.z;
        Pb.w = fmaf(As[i].w, Pb.w, Bs[i].w); Pa.w = As[i].w * Pa.w;
    }
    // inclusive suffix scan across 32 slices: P_k = M_k o M_{k+1} o ... o M_31
    #pragma unroll
    for (int d = 1; d < 32; d <<= 1) {
        const float nax = __shfl_down(Pa.x, d, 32), nay = __shfl_down(Pa.y, d, 32);
        const float naz = __shfl_down(Pa.z, d, 32), naw = __shfl_down(Pa.w, d, 32);
        const float nbx = __shfl_down(Pb.x, d, 32), nby = __shfl_down(Pb.y, d, 32);
        const float nbz = __shfl_down(Pb.z, d, 32), nbw = __shfl_down(Pb.w, d, 32);
        if (k + d < 32) {               // compose: current o neighbor
            Pb.x = fmaf(Pa.x, nbx, Pb.x); Pa.x *= nax;
            Pb.y = fmaf(Pa.y, nby, Pb.y); Pa.y *= nay;
            Pb.z = fmaf(Pa.z, nbz, Pb.z); Pa.z *= naz;
            Pb.w = fmaf(Pa.w, nbw, Pb.w); Pa.w *= naw;
        }
    }
    // incoming gae for slice k = P_{k+1}(0) = B of lane k+1 (0 for k==31)
    float4 G;
    G.x = __shfl_down(Pb.x, 1, 32);
    G.y = __shfl_down(Pb.y, 1, 32);
    G.z = __shfl_down(Pb.z, 1, 32);
    G.w = __shfl_down(Pb.w, 1, 32);
    if (k == 31) G = make_float4(0.f, 0.f, 0.f, 0.f);
    // back-fill per-chunk incoming gae (highest chunk of slice first)
    #pragma unroll
    for (int i = 7; i >= 0; --i) {
        Ag[(8 * k + i) * NV4 + jj] = G;
        G.x = fmaf(As[i].x, G.x, Bs[i].x);
        G.y = fmaf(As[i].y, G.y, Bs[i].y);
        G.z = fmaf(As[i].z, G.z, Bs[i].z);
        G.w = fmaf(As[i].w, G.w, Bs[i].w);
    }
}

// ---------------------------------------------------------------------------
// K3: recompute gae from b16 + g_in (row-serial, L_CHUNK=4); fuse value loss
// and sum/sum2 of gae. Block partials -> pg. No gae store.
__device__ __forceinline__ void gae_comp(float& gae, unsigned short h,
                                         float v, float nvv,
                                         float& sg, float& sg2, float& v_s) {
    const float bf = bf2f(h);
    const float a  = (h & 1u) ? kGLAM : 0.0f;
    gae = fmaf(a, gae, bf);
    sg += gae;
    sg2 = fmaf(gae, gae, sg2);
    const float q  = nvv - v;
    const float e1 = q - gae;
    const float e2 = fminf(fmaxf(q, -0.2f), 0.2f) - gae;
    v_s += fmaxf(e1 * e1, e2 * e2);
}

__global__ __launch_bounds__(256, 8) void k_gae(
    const ushort4* __restrict__ b16,
    const float4* __restrict__ g_in4,
    const float4* __restrict__ vp4,
    const float4* __restrict__ nv4,
    double* __restrict__ pg)           // [PC_BLOCKS][3]
{
    const int g  = blockIdx.x * 256 + threadIdx.x;
    const int j  = g & (NV4 - 1);
    const int c  = g >> 11;
    const int t0 = c * L_CHUNK;

    float4 gae = g_in4[c * NV4 + j];
    float sg = 0.f, sg2 = 0.f, v_s = 0.f;

    #pragma unroll
    for (int i = L_CHUNK - 1; i >= 0; --i) {
        const int idx = (t0 + i) * NV4 + j;
        const ushort4 h = b16[idx];
        const float4  v = vp4[idx];
        const float4  q = nv4[idx];
        gae_comp(gae.x, h.x, v.x, q.x, sg, sg2, v_s);
        gae_comp(gae.y, h.y, v.y, q.y, sg, sg2, v_s);
        gae_comp(gae.z, h.z, v.z, q.z, sg, sg2, v_s);
        gae_comp(gae.w, h.w, v.w, q.w, sg, sg2, v_s);
    }

    double d0 = (double)sg, d1 = (double)sg2, d2 = (double)v_s;
    #pragma unroll
    for (int off = 32; off > 0; off >>= 1) {
        d0 += __shfl_down(d0, off, 64);
        d1 += __shfl_down(d1, off, 64);
        d2 += __shfl_down(d2, off, 64);
    }
    __shared__ double sh[3][4];
    const int wid = threadIdx.x >> 6, lane = threadIdx.x & 63;
    if (lane == 0) { sh[0][wid] = d0; sh[1][wid] = d1; sh[2][wid] = d2; }
    __syncthreads();
    if (threadIdx.x == 0) {
        double t0s = 0, t1s = 0, t2s = 0;
        #pragma unroll
        for (int w = 0; w < 4; ++w) { t0s += sh[0][w]; t1s += sh[1][w]; t2s += sh[2][w]; }
        pg[blockIdx.x * 3 + 0] = t0s;
        pg[blockIdx.x * 3 + 1] = t1s;
        pg[blockIdx.x * 3 + 2] = t2s;
    }
}

// ---------------------------------------------------------------------------
// K4: action loss + entropy (L_CHUNK=4). Absorbs k_stats: every block
// redundantly reduces the 48 KB pg partials (L2-resident) to mu/invs, then
// recomputes gae in fp32 from b16 + g_in. Partials -> pl.
__global__ __launch_bounds__(256, 6) void k_loss(
    const ushort4* __restrict__ b16,
    const float4* __restrict__ g_in4,
    const float4* __restrict__ lp4,
    const float4* __restrict__ plp4,
    const float4* __restrict__ ent4,
    const double* __restrict__ pg,
    double* __restrict__ pl)           // [PC_BLOCKS][2]
{
    __shared__ double sh[2][4];
    __shared__ double bc[2];
    const int tid = threadIdx.x;

    // --- redundant stats reduce (mu, invs) ---
    {
        double s0 = 0.0, s1 = 0.0;
        for (int i = tid; i < PC_BLOCKS; i += 256) {
            s0 += pg[i * 3 + 0];
            s1 += pg[i * 3 + 1];
        }
        #pragma unroll
        for (int off = 32; off > 0; off >>= 1) {
            s0 += __shfl_down(s0, off, 64);
            s1 += __shfl_down(s1, off, 64);
        }
        const int wid = tid >> 6, lane = tid & 63;
        if (lane == 0) { sh[0][wid] = s0; sh[1][wid] = s1; }
        __syncthreads();
        if (tid == 0) {
            double sum = 0, sum2 = 0;
            #pragma unroll
            for (int w = 0; w < 4; ++w) { sum += sh[0][w]; sum2 += sh[1][w]; }
            const double M = (double)M_TOT;
            const double mu = sum / M;
            double var = (sum2 - sum * sum / M) / (M - 1.0);
            if (var < 0.0) var = 0.0;
            bc[0] = mu;
            bc[1] = 1.0 / (sqrt(var) + 1e-5);
        }
        __syncthreads();
    }
    const float mu   = (float)bc[0];
    const float invs = (float)bc[1];

    // --- loss over this block's chunk (same geometry as K3) ---
    const int g  = blockIdx.x * 256 + tid;
    const int j  = g & (NV4 - 1);
    const int c  = g >> 11;
    const int t0 = c * L_CHUNK;

    float4 gv = g_in4[c * NV4 + j];
    float a_s = 0.f, e_s = 0.f;

    #pragma unroll
    for (int i = L_CHUNK - 1; i >= 0; --i) {
        const int idx = (t0 + i) * NV4 + j;
        const ushort4 h = b16[idx];
        const float4 Lp = lp4[idx];
        const float4 Pp = plp4[idx];
        const float4 E  = ent4[idx];
#define P5C(comp, H) { \
        const unsigned short hh = (H); \
        const float bf = bf2f(hh); \
        const float a  = (hh & 1u) ? kGLAM : 0.0f; \
        gv.comp = fmaf(a, gv.comp, bf); \
        const float x  = (gv.comp - mu) * invs; \
        const float rr = __expf(Lp.comp - Pp.comp); \
        const float rc = fminf(fmaxf(rr, 0.8f), 1.2f); \
        a_s += fminf(rr * x, rc * x); }
        P5C(x, h.x) P5C(y, h.y) P5C(z, h.z) P5C(w, h.w)
#undef P5C
        e_s += E.x + E.y + E.z + E.w;
    }

    double d0 = (double)a_s, d1 = (double)e_s;
    #pragma unroll
    for (int off = 32; off > 0; off >>= 1) {
        d0 += __shfl_down(d0, off, 64);
        d1 += __shfl_down(d1, off, 64);
    }
    const int wid = tid >> 6, lane = tid & 63;
    if (lane == 0) { sh[0][wid] = d0; sh[1][wid] = d1; }
    __syncthreads();
    if (tid == 0) {
        double t0s = 0, t1s = 0;
        #pragma unroll
        for (int w = 0; w < 4; ++w) { t0s += sh[0][w]; t1s += sh[1][w]; }
        pl[blockIdx.x * 2 + 0] = t0s;
        pl[blockIdx.x * 2 + 1] = t1s;
    }
}

// ---------------------------------------------------------------------------
// K5: reduce k_gae vsum partials + k_loss partials -> final scalar.
__global__ __launch_bounds__(256) void k_final(
    const double* __restrict__ pg, const double* __restrict__ pl,
    float* __restrict__ out)
{
    double s0 = 0.0, s1 = 0.0, s2 = 0.0;
    for (int i = threadIdx.x; i < PC_BLOCKS; i += 256) {
        s0 += pl[i * 2 + 0];
        s1 += pl[i * 2 + 1];
        s2 += pg[i * 3 + 2];
    }
    #pragma unroll
    for (int off = 32; off > 0; off >>= 1) {
        s0 += __shfl_down(s0, off, 64);
        s1 += __shfl_down(s1, off, 64);
        s2 += __shfl_down(s2, off, 64);
    }
    __shared__ double sh[3][4];
    const int wid = threadIdx.x >> 6, lane = threadIdx.x & 63;
    if (lane == 0) { sh[0][wid] = s0; sh[1][wid] = s1; sh[2][wid] = s2; }
    __syncthreads();
    if (threadIdx.x == 0) {
        double a_sum = 0, e_sum = 0, vsum = 0;
        #pragma unroll
        for (int w = 0; w < 4; ++w) { a_sum += sh[0][w]; e_sum += sh[1][w]; vsum += sh[2][w]; }
        const double M = (double)M_TOT;
        out[0] = (float)(0.25 * vsum / M - a_sum / M - 0.01 * e_sum / M);
    }
}

// ---------------------------------------------------------------------------
extern "C" void kernel_launch(void* const* d_in, const int* in_sizes, int n_in,
                              void* d_out, int out_size, void* d_ws, size_t ws_size,
                              hipStream_t stream) {
    const float* rewards     = (const float*)d_in[0];   // (T, N)
    const float* masks       = (const float*)d_in[1];   // (T+1, N)
    const float* bad_masks   = (const float*)d_in[2];   // (T+1, N)
    const float* value_preds = (const float*)d_in[3];   // (T+1, N)
    const float* last_value  = (const float*)d_in[4];   // (N,)
    const float* log_prob    = (const float*)d_in[5];   // (T, N)
    const float* prev_lp     = (const float*)d_in[6];   // (T, N)
    const float* new_value   = (const float*)d_in[7];   // (T, N)
    const float* dist_ent    = (const float*)d_in[8];   // (T, N)

    char* ws = (char*)d_ws;
    double* pg = (double*)(ws + 1024);
    double* pl = (double*)(ws + 65536);
    unsigned short* b16 = (unsigned short*)(ws + 131072);
    float* A = (float*)(ws + 131072 + (size_t)M_TOT * 2);
    float* B = (float*)(ws + 131072 + (size_t)M_TOT * 2 + (size_t)C_CHUNKS * N_DIM * 4);

    k_pc<<<PC_BLOCKS, 256, 0, stream>>>((const float4*)rewards,
                                        (const float4*)masks,
                                        (const float4*)bad_masks,
                                        (const float4*)value_preds,
                                        (const float4*)last_value,
                                        (ushort4*)b16, (float4*)A, (float4*)B);
    k_scan<<<SCAN_BLOCKS, 256, 0, stream>>>((float4*)A, (const float4*)B);
    k_gae<<<PC_BLOCKS, 256, 0, stream>>>((const ushort4*)b16,
                                         (const float4*)A /* g_in */,
                                         (const float4*)value_preds,
                                         (const float4*)new_value, pg);
    k_loss<<<PC_BLOCKS, 256, 0, stream>>>((const ushort4*)b16,
                                          (const float4*)A /* g_in */,
                                          (const float4*)log_prob,
                                          (const float4*)prev_lp,
                                          (const float4*)dist_ent, pg, pl);
    k_final<<<1, 256, 0, stream>>>(pg, pl, (float*)d_out);
}

// Round 5
// 272.455 us; speedup vs baseline: 1.0245x; 1.0055x over previous
//
#include <hip/hip_runtime.h>
#include <math.h>

// Problem constants
#define T_DIM 1024
#define N_DIM 8192
#define M_TOT (T_DIM * N_DIM)          // 8,388,608
#define NV4   (N_DIM / 4)              // 2048 float4 per row
#define L_CHUNK 8
#define C_CHUNKS (T_DIM / L_CHUNK)     // 128
#define PC_BLOCKS ((C_CHUNKS * NV4) / 256)   // 1024
#define SCAN_BLOCKS ((NV4 * 32) / 256)       // 256  (32 slices x 4 chunks)

#define kGAMMA 0.99f
#define kGLAM  (0.99f * 0.95f)

// ws layout (~24.06 MB):
//   [0,64)        acc doubles: 3=value sum, 5=mu, 6=inv(std+1e-5)
//   +256          pg [1024][3] doubles (24 KB)
//   +32768        pl [1024][2] doubles (16 KB)
//   +65536        b16 [T][N] ushort (16 MB)
//   +65536+16MB   A   [C][N] float (4 MB)  -- chunk-map A, overwritten w/ g_in
//   +65536+20MB   B   [C][N] float (4 MB)

__device__ __forceinline__ unsigned short f2bf(float f) {
    unsigned int u = __float_as_uint(f);
    u += 0x7fffu + ((u >> 16) & 1u);        // round-to-nearest-even
    return (unsigned short)(u >> 16);
}
__device__ __forceinline__ float bf2f(unsigned short h) {
    return __uint_as_float(((unsigned int)h) << 16);
}

// ---------------------------------------------------------------------------
// K1: fused prep+chunk, float4 geometry, L_CHUNK=8, BATCHED LOADS.
// Two batches of 4 t-steps: issue all 16 float4 loads, then compute.
// launch_bounds(256,4): VGPR cap 128 -> deep load pipelining + 16 waves/CU.
__global__ __launch_bounds__(256, 4) void k_pc(
    const float4* __restrict__ r4,
    const float4* __restrict__ m4,     // (T+1) rows
    const float4* __restrict__ bm4,    // (T+1) rows
    const float4* __restrict__ vp4,    // (T+1) rows
    const float4* __restrict__ lv4,    // (N,)
    ushort4* __restrict__ b16,
    float4* __restrict__ A_out,
    float4* __restrict__ B_out)
{
    const int g  = blockIdx.x * 256 + threadIdx.x;   // 0 .. C*NV4-1
    const int j  = g & (NV4 - 1);
    const int c  = g >> 11;
    const int t0 = c * L_CHUNK;

    float4 vnext = (c == C_CHUNKS - 1) ? lv4[j] : vp4[(t0 + L_CHUNK) * NV4 + j];
    float4 Aa = make_float4(1.f, 1.f, 1.f, 1.f);
    float4 Bb = make_float4(0.f, 0.f, 0.f, 0.f);

    #pragma unroll
    for (int half = 0; half < 2; ++half) {
        const int ibase = (half == 0) ? 7 : 3;       // i = ibase-u, u=0..3
        float4 R[4], V[4], M[4], BBv[4];
        #pragma unroll
        for (int u = 0; u < 4; ++u) {                // batch all 16 loads
            const int idx = (t0 + ibase - u) * NV4 + j;
            R[u]   = r4[idx];
            V[u]   = vp4[idx];
            M[u]   = m4[idx + NV4];                  // row t+1
            BBv[u] = bm4[idx + NV4];                 // row t+1
        }
        #pragma unroll
        for (int u = 0; u < 4; ++u) {                // then compute (descending t)
            ushort4 o;
#define P1C(comp) { \
            const float b = (fmaf(kGAMMA * M[u].comp, vnext.comp, R[u].comp) - V[u].comp) * BBv[u].comp; \
            const float a = kGLAM * M[u].comp * BBv[u].comp; \
            Aa.comp = a * Aa.comp; Bb.comp = fmaf(a, Bb.comp, b); \
            o.comp = (unsigned short)((f2bf(b) & 0xFFFEu) | ((M[u].comp * BBv[u].comp > 0.5f) ? 1u : 0u)); }
            P1C(x) P1C(y) P1C(z) P1C(w)
#undef P1C
            b16[(t0 + ibase - u) * NV4 + j] = o;
            vnext = V[u];
        }
    }
    A_out[c * NV4 + j] = Aa;
    B_out[c * NV4 + j] = Bb;
}

// ---------------------------------------------------------------------------
// K2: parallel suffix scan of the 128 affine chunk maps (verified bit-exact,
// round 3). Thread (jj, k): slice k = chunks 4k..4k+3; 32-lane shuffle groups
// share one jj. g_in overwrites Ag (one thread owns each slot).
__global__ __launch_bounds__(256, 8) void k_scan(
    float4* __restrict__ Ag,           // in: A, out: g_in
    const float4* __restrict__ Bg)
{
    const int u  = blockIdx.x * 256 + threadIdx.x;   // 0 .. NV4*32-1
    const int jj = u >> 5;
    const int k  = u & 31;

    float4 As[4], Bs[4];
    #pragma unroll
    for (int i = 0; i < 4; ++i) {
        As[i] = Ag[(4 * k + i) * NV4 + jj];
        Bs[i] = Bg[(4 * k + i) * NV4 + jj];
    }
    // slice map M_k = f_{4k} o ... o f_{4k+3} (highest chunk applied first)
    float4 Pa = As[3], Pb = Bs[3];
    #pragma unroll
    for (int i = 2; i >= 0; --i) {
        Pb.x = fmaf(As[i].x, Pb.x, Bs[i].x); Pa.x = As[i].x * Pa.x;
        Pb.y = fmaf(As[i].y, Pb.y, Bs[i].y); Pa.y = As[i].y * Pa.y;
        Pb.z = fmaf(As[i].z, Pb.z, Bs[i].z); Pa.z = As[i].z * Pa.z;
        Pb.w = fmaf(As[i].w, Pb.w, Bs[i].w); Pa.w = As[i].w * Pa.w;
    }
    // inclusive suffix scan across 32 slices
    #pragma unroll
    for (int d = 1; d < 32; d <<= 1) {
        const float nax = __shfl_down(Pa.x, d, 32), nay = __shfl_down(Pa.y, d, 32);
        const float naz = __shfl_down(Pa.z, d, 32), naw = __shfl_down(Pa.w, d, 32);
        const float nbx = __shfl_down(Pb.x, d, 32), nby = __shfl_down(Pb.y, d, 32);
        const float nbz = __shfl_down(Pb.z, d, 32), nbw = __shfl_down(Pb.w, d, 32);
        if (k + d < 32) {               // compose: current o neighbor
            Pb.x = fmaf(Pa.x, nbx, Pb.x); Pa.x *= nax;
            Pb.y = fmaf(Pa.y, nby, Pb.y); Pa.y *= nay;
            Pb.z = fmaf(Pa.z, nbz, Pb.z); Pa.z *= naz;
            Pb.w = fmaf(Pa.w, nbw, Pb.w); Pa.w *= naw;
        }
    }
    // incoming gae for slice k = P_{k+1}(0) = B of lane k+1 (0 for k==31)
    float4 G;
    G.x = __shfl_down(Pb.x, 1, 32);
    G.y = __shfl_down(Pb.y, 1, 32);
    G.z = __shfl_down(Pb.z, 1, 32);
    G.w = __shfl_down(Pb.w, 1, 32);
    if (k == 31) G = make_float4(0.f, 0.f, 0.f, 0.f);
    // back-fill per-chunk incoming gae (highest chunk of slice first)
    #pragma unroll
    for (int i = 3; i >= 0; --i) {
        Ag[(4 * k + i) * NV4 + jj] = G;
        G.x = fmaf(As[i].x, G.x, Bs[i].x);
        G.y = fmaf(As[i].y, G.y, Bs[i].y);
        G.z = fmaf(As[i].z, G.z, Bs[i].z);
        G.w = fmaf(As[i].w, G.w, Bs[i].w);
    }
}

// ---------------------------------------------------------------------------
// K3: recompute gae from b16 + g_in (row-serial, L_CHUNK=8), BATCHED LOADS:
// all 24 loads (8x ushort4 + 8x float4 + 8x float4) issued before compute.
// Fuse value loss and sum/sum2 of gae. Block partials -> pg.
__global__ __launch_bounds__(256, 4) void k_gae(
    const ushort4* __restrict__ b16,
    const float4* __restrict__ g_in4,
    const float4* __restrict__ vp4,
    const float4* __restrict__ nv4,
    double* __restrict__ pg)           // [PC_BLOCKS][3]
{
    const int g  = blockIdx.x * 256 + threadIdx.x;
    const int j  = g & (NV4 - 1);
    const int c  = g >> 11;
    const int t0 = c * L_CHUNK;

    float4 gae = g_in4[c * NV4 + j];
    float sg = 0.f, sg2 = 0.f, v_s = 0.f;

    ushort4 H[8]; float4 V[8], Q[8];
    #pragma unroll
    for (int u = 0; u < 8; ++u) {                    // i = 7-u; batch all loads
        const int idx = (t0 + 7 - u) * NV4 + j;
        H[u] = b16[idx];
        V[u] = vp4[idx];
        Q[u] = nv4[idx];
    }
    #pragma unroll
    for (int u = 0; u < 8; ++u) {
#define P3C(comp, HH) { \
        const unsigned short h = (HH); \
        const float bf = bf2f(h); \
        const float a  = (h & 1u) ? kGLAM : 0.0f; \
        gae.comp = fmaf(a, gae.comp, bf); \
        sg += gae.comp; sg2 = fmaf(gae.comp, gae.comp, sg2); \
        const float qd = Q[u].comp - V[u].comp; \
        const float e1 = qd - gae.comp; \
        const float e2 = fminf(fmaxf(qd, -0.2f), 0.2f) - gae.comp; \
        v_s += fmaxf(e1 * e1, e2 * e2); }
        P3C(x, H[u].x) P3C(y, H[u].y) P3C(z, H[u].z) P3C(w, H[u].w)
#undef P3C
    }

    double d0 = (double)sg, d1 = (double)sg2, d2 = (double)v_s;
    #pragma unroll
    for (int off = 32; off > 0; off >>= 1) {
        d0 += __shfl_down(d0, off, 64);
        d1 += __shfl_down(d1, off, 64);
        d2 += __shfl_down(d2, off, 64);
    }
    __shared__ double sh[3][4];
    const int wid = threadIdx.x >> 6, lane = threadIdx.x & 63;
    if (lane == 0) { sh[0][wid] = d0; sh[1][wid] = d1; sh[2][wid] = d2; }
    __syncthreads();
    if (threadIdx.x == 0) {
        double t0s = 0, t1s = 0, t2s = 0;
        #pragma unroll
        for (int w = 0; w < 4; ++w) { t0s += sh[0][w]; t1s += sh[1][w]; t2s += sh[2][w]; }
        pg[blockIdx.x * 3 + 0] = t0s;
        pg[blockIdx.x * 3 + 1] = t1s;
        pg[blockIdx.x * 3 + 2] = t2s;
    }
}

// ---------------------------------------------------------------------------
// K4: reduce k_gae partials -> mu, inv(std+eps), value sum. One block.
__global__ __launch_bounds__(256) void k_stats(
    const double* __restrict__ pg, double* __restrict__ acc)
{
    double s0 = 0.0, s1 = 0.0, s2 = 0.0;
    for (int i = threadIdx.x; i < PC_BLOCKS; i += 256) {
        s0 += pg[i * 3 + 0];
        s1 += pg[i * 3 + 1];
        s2 += pg[i * 3 + 2];
    }
    #pragma unroll
    for (int off = 32; off > 0; off >>= 1) {
        s0 += __shfl_down(s0, off, 64);
        s1 += __shfl_down(s1, off, 64);
        s2 += __shfl_down(s2, off, 64);
    }
    __shared__ double sh[3][4];
    const int wid = threadIdx.x >> 6, lane = threadIdx.x & 63;
    if (lane == 0) { sh[0][wid] = s0; sh[1][wid] = s1; sh[2][wid] = s2; }
    __syncthreads();
    if (threadIdx.x == 0) {
        double sum = 0, sum2 = 0, vsum = 0;
        #pragma unroll
        for (int w = 0; w < 4; ++w) { sum += sh[0][w]; sum2 += sh[1][w]; vsum += sh[2][w]; }
        const double M = (double)M_TOT;
        const double mu = sum / M;
        double var = (sum2 - sum * sum / M) / (M - 1.0);
        if (var < 0.0) var = 0.0;
        acc[3] = vsum;
        acc[5] = mu;
        acc[6] = 1.0 / (sqrt(var) + 1e-5);
    }
}

// ---------------------------------------------------------------------------
// K5: action loss + entropy (L_CHUNK=8 geometry), BATCHED LOADS in two halves
// of 4 t-steps (14 regs/step). mu/invs from acc (uniform scalar loads).
__global__ __launch_bounds__(256, 4) void k_loss(
    const ushort4* __restrict__ b16,
    const float4* __restrict__ g_in4,
    const float4* __restrict__ lp4,
    const float4* __restrict__ plp4,
    const float4* __restrict__ ent4,
    const double* __restrict__ acc,
    double* __restrict__ pl)           // [PC_BLOCKS][2]
{
    const int tid = threadIdx.x;
    const int g  = blockIdx.x * 256 + tid;
    const int j  = g & (NV4 - 1);
    const int c  = g >> 11;
    const int t0 = c * L_CHUNK;

    const float mu   = (float)acc[5];
    const float invs = (float)acc[6];

    float4 gv = g_in4[c * NV4 + j];
    float a_s = 0.f, e_s = 0.f;

    #pragma unroll
    for (int half = 0; half < 2; ++half) {
        const int ibase = (half == 0) ? 7 : 3;       // i = ibase-u, u=0..3
        ushort4 H[4]; float4 L[4], P[4], E[4];
        #pragma unroll
        for (int u = 0; u < 4; ++u) {                // batch all 16 loads
            const int idx = (t0 + ibase - u) * NV4 + j;
            H[u] = b16[idx];
            L[u] = lp4[idx];
            P[u] = plp4[idx];
            E[u] = ent4[idx];
        }
        #pragma unroll
        for (int u = 0; u < 4; ++u) {
#define P5C(comp, HH) { \
            const unsigned short hh = (HH); \
            const float bf = bf2f(hh); \
            const float a  = (hh & 1u) ? kGLAM : 0.0f; \
            gv.comp = fmaf(a, gv.comp, bf); \
            const float x  = (gv.comp - mu) * invs; \
            const float rr = __expf(L[u].comp - P[u].comp); \
            const float rc = fminf(fmaxf(rr, 0.8f), 1.2f); \
            a_s += fminf(rr * x, rc * x); }
            P5C(x, H[u].x) P5C(y, H[u].y) P5C(z, H[u].z) P5C(w, H[u].w)
#undef P5C
            e_s += E[u].x + E[u].y + E[u].z + E[u].w;
        }
    }

    double d0 = (double)a_s, d1 = (double)e_s;
    #pragma unroll
    for (int off = 32; off > 0; off >>= 1) {
        d0 += __shfl_down(d0, off, 64);
        d1 += __shfl_down(d1, off, 64);
    }
    __shared__ double sh[2][4];
    const int wid = tid >> 6, lane = tid & 63;
    if (lane == 0) { sh[0][wid] = d0; sh[1][wid] = d1; }
    __syncthreads();
    if (tid == 0) {
        double t0s = 0, t1s = 0;
        #pragma unroll
        for (int w = 0; w < 4; ++w) { t0s += sh[0][w]; t1s += sh[1][w]; }
        pl[blockIdx.x * 2 + 0] = t0s;
        pl[blockIdx.x * 2 + 1] = t1s;
    }
}

// ---------------------------------------------------------------------------
// K6: reduce k_loss partials + combine with value sum -> final scalar.
__global__ __launch_bounds__(256) void k_final(
    const double* __restrict__ pl, const double* __restrict__ acc,
    float* __restrict__ out)
{
    double s0 = 0.0, s1 = 0.0;
    for (int i = threadIdx.x; i < PC_BLOCKS; i += 256) {
        s0 += pl[i * 2 + 0];
        s1 += pl[i * 2 + 1];
    }
    #pragma unroll
    for (int off = 32; off > 0; off >>= 1) {
        s0 += __shfl_down(s0, off, 64);
        s1 += __shfl_down(s1, off, 64);
    }
    __shared__ double sh[2][4];
    const int wid = threadIdx.x >> 6, lane = threadIdx.x & 63;
    if (lane == 0) { sh[0][wid] = s0; sh[1][wid] = s1; }
    __syncthreads();
    if (threadIdx.x == 0) {
        double a_sum = 0, e_sum = 0;
        #pragma unroll
        for (int w = 0; w < 4; ++w) { a_sum += sh[0][w]; e_sum += sh[1][w]; }
        const double M = (double)M_TOT;
        out[0] = (float)(0.25 * acc[3] / M - a_sum / M - 0.01 * e_sum / M);
    }
}

// ---------------------------------------------------------------------------
extern "C" void kernel_launch(void* const* d_in, const int* in_sizes, int n_in,
                              void* d_out, int out_size, void* d_ws, size_t ws_size,
                              hipStream_t stream) {
    const float* rewards     = (const float*)d_in[0];   // (T, N)
    const float* masks       = (const float*)d_in[1];   // (T+1, N)
    const float* bad_masks   = (const float*)d_in[2];   // (T+1, N)
    const float* value_preds = (const float*)d_in[3];   // (T+1, N)
    const float* last_value  = (const float*)d_in[4];   // (N,)
    const float* log_prob    = (const float*)d_in[5];   // (T, N)
    const float* prev_lp     = (const float*)d_in[6];   // (T, N)
    const float* new_value   = (const float*)d_in[7];   // (T, N)
    const float* dist_ent    = (const float*)d_in[8];   // (T, N)

    char* ws = (char*)d_ws;
    double* acc = (double*)ws;
    double* pg  = (double*)(ws + 256);
    double* pl  = (double*)(ws + 32768);
    unsigned short* b16 = (unsigned short*)(ws + 65536);
    float* A = (float*)(ws + 65536 + (size_t)M_TOT * 2);
    float* B = (float*)(ws + 65536 + (size_t)M_TOT * 2 + (size_t)C_CHUNKS * N_DIM * 4);

    k_pc<<<PC_BLOCKS, 256, 0, stream>>>((const float4*)rewards,
                                        (const float4*)masks,
                                        (const float4*)bad_masks,
                                        (const float4*)value_preds,
                                        (const float4*)last_value,
                                        (ushort4*)b16, (float4*)A, (float4*)B);
    k_scan<<<SCAN_BLOCKS, 256, 0, stream>>>((float4*)A, (const float4*)B);
    k_gae<<<PC_BLOCKS, 256, 0, stream>>>((const ushort4*)b16,
                                         (const float4*)A /* g_in */,
                                         (const float4*)value_preds,
                                         (const float4*)new_value, pg);
    k_stats<<<1, 256, 0, stream>>>(pg, acc);
    k_loss<<<PC_BLOCKS, 256, 0, stream>>>((const ushort4*)b16,
                                          (const float4*)A /* g_in */,
                                          (const float4*)log_prob,
                                          (const float4*)prev_lp,
                                          (const float4*)dist_ent, acc, pl);
    k_final<<<1, 256, 0, stream>>>(pl, acc, (float*)d_out);
}